// Round 1
// baseline (184.934 us; speedup 1.0000x reference)
//
#include <hip/hip_runtime.h>
#include <math.h>

#define IMG_W 3840
#define IMG_H 2160
#define TW 128
#define TH 16

// dx table [1,1,0,-1,-1,-1,0,1] packed as (dx+1) 2-bit fields
// dy table [0,1,1,1,0,-1,-1,-1] packed as (dy+1) 2-bit fields
#define DXPACK 0x901A
#define DYPACK 0x1A9

__global__ __launch_bounds__(256) void canny_like_kernel(const float* __restrict__ img,
                                                         float* __restrict__ out) {
#pragma clang fp contract(off)
    const float RADF = (float)(180.0 / 3.14159);  // module constant, not pi

    __shared__ float lds_g[TH + 4][TW + 4];  // gray, halo 2
    __shared__ float lds_m[TH + 2][TW + 2];  // grad magnitude, halo 1

    const int tx = threadIdx.x;              // 0..127
    const int ty = threadIdx.y;              // 0..1
    const int tid = ty * TW + tx;            // 0..255
    const int x0 = blockIdx.x * TW;
    const int y0 = blockIdx.y * TH;

    // ---- Stage 1: grayscale into LDS (tile + halo 2), zero outside image ----
    for (int i = tid; i < (TH + 4) * (TW + 4); i += 256) {
        int ry = i / (TW + 4);
        int rx = i - ry * (TW + 4);
        int gyy = y0 - 2 + ry;
        int gxx = x0 - 2 + rx;
        float v = 0.0f;
        if (gyy >= 0 && gyy < IMG_H && gxx >= 0 && gxx < IMG_W) {
            int base = gyy * IMG_W + gxx;
            float c0 = img[base];
            float c1 = img[base + IMG_H * IMG_W];
            float c2 = img[base + 2 * IMG_H * IMG_W];
            v = ((c0 + c1) + c2) / 3.0f;     // left-assoc, true division (match ref)
        }
        lds_g[ry][rx] = v;
    }
    __syncthreads();

    // ---- Stage 2: gradient magnitude into LDS (tile + halo 1) ----
    // mag at OOB positions must be 0 (SAME zero padding of the dir-filter conv).
    for (int i = tid; i < (TH + 2) * (TW + 2); i += 256) {
        int my = i / (TW + 2);
        int mx = i - my * (TW + 2);
        int gyy = y0 - 1 + my;
        int gxx = x0 - 1 + mx;
        float v = 0.0f;
        if (gyy >= 0 && gyy < IMG_H && gxx >= 0 && gxx < IMG_W) {
            float a00 = lds_g[my][mx],     a01 = lds_g[my][mx + 1],     a02 = lds_g[my][mx + 2];
            float a10 = lds_g[my + 1][mx],                              a12 = lds_g[my + 1][mx + 2];
            float a20 = lds_g[my + 2][mx], a21 = lds_g[my + 2][mx + 1], a22 = lds_g[my + 2][mx + 2];
            // sobel_h row-major taps: [1 0 -1; 2 0 -2; 1 0 -1]  (cross-correlation)
            float sx = a00;
            sx = sx - a02;
            sx = sx + 2.0f * a10;
            sx = sx - 2.0f * a12;
            sx = sx + a20;
            sx = sx - a22;
            // sobel_v = sobel^T: [1 2 1; 0 0 0; -1 -2 -1]
            float sy = a00;
            sy = sy + 2.0f * a01;
            sy = sy + a02;
            sy = sy - a20;
            sy = sy - 2.0f * a21;
            sy = sy - a22;
            v = sqrtf(sx * sx + sy * sy);    // contraction off -> mul,mul,add,sqrt all IEEE
        }
        lds_m[my][mx] = v;
    }
    __syncthreads();

    // ---- Stage 3: orientation + NMS + threshold ----
    for (int r = 0; r < TH / 2; ++r) {
        int oy = r * 2 + ty;                 // 0..15
        int my = oy + 1, mx = tx + 1;        // mag LDS coords of center
        int ry = oy + 2, rx = tx + 2;        // gray LDS coords of center
        float a00 = lds_g[ry - 1][rx - 1], a01 = lds_g[ry - 1][rx], a02 = lds_g[ry - 1][rx + 1];
        float a10 = lds_g[ry][rx - 1],                              a12 = lds_g[ry][rx + 1];
        float a20 = lds_g[ry + 1][rx - 1], a21 = lds_g[ry + 1][rx], a22 = lds_g[ry + 1][rx + 1];
        float sx = a00;
        sx = sx - a02;
        sx = sx + 2.0f * a10;
        sx = sx - 2.0f * a12;
        sx = sx + a20;
        sx = sx - a22;
        float sy = a00;
        sy = sy + 2.0f * a01;
        sy = sy + a02;
        sy = sy - a20;
        sy = sy - 2.0f * a21;
        sy = sy - a22;

        float t = atan2f(sy, sx);
        float wv = ((t * RADF) + 180.0f) / 45.0f;   // exact f32 chain as reference
        float ori = rintf(wv);                      // round-half-even == np.round
        float fr = fabsf(wv - ori);
        if (fr > 0.4995f) {
            // near a rounding tie: redo atan2 in double -> correctly-rounded f32,
            // best match for the host libm's atan2f
            double td = atan2((double)sy, (double)sx);
            float t2 = (float)td;
            wv = ((t2 * RADF) + 180.0f) / 45.0f;
            ori = rintf(wv);
        }
        int idx = ((int)ori) & 7;                   // mod(ori, 8); ori in [0, 8]
        int dxo = ((DXPACK >> (2 * idx)) & 3) - 1;
        int dyo = ((DYPACK >> (2 * idx)) & 3) - 1;

        float mc = lds_m[my][mx];
        float pos = mc - lds_m[my + dyo][mx + dxo];  // dir filter idx applied at p
        float neg = mc - lds_m[my - dyo][mx - dxo];  // dir filter idx+4 (opposite offset)
        float res = (fminf(pos, neg) > 0.0f && mc >= 0.2f) ? 1.0f : 0.0f;
        out[(y0 + oy) * IMG_W + (x0 + tx)] = res;
    }
}

extern "C" void kernel_launch(void* const* d_in, const int* in_sizes, int n_in,
                              void* d_out, int out_size, void* d_ws, size_t ws_size,
                              hipStream_t stream) {
    const float* img = (const float*)d_in[0];
    float* out = (float*)d_out;
    // 3840 = 30*128, 2160 = 135*16 -> exact tiling, no partial tiles
    dim3 grid(IMG_W / TW, IMG_H / TH);
    dim3 block(TW, 2);
    canny_like_kernel<<<grid, block, 0, stream>>>(img, out);
}

// Round 2
// 178.497 us; speedup vs baseline: 1.0361x; 1.0361x over previous
//
#include <hip/hip_runtime.h>
#include <math.h>

#define IMG_W 3840
#define IMG_H 2160
#define TW 128
#define TH 16

// dx table [1,1,0,-1,-1,-1,0,1] packed as (dx+1) 2-bit fields
// dy table [0,1,1,1,0,-1,-1,-1] packed as (dy+1) 2-bit fields
#define DXPACK 0x901A
#define DYPACK 0x1A9

// Sector boundary slopes in the module's scaled-degree space (RAD2DEG = 180/3.14159):
// tan(22.5 * 3.14159/180) and tan(67.5 * 3.14159/180)
#define T1_SLOPE 0.41421317376456f
#define T2_SLOPE 2.41420676743300f
// relative margin below which we can't trust the fast sector test vs f32 atan2 rounding
#define SECT_EPS 3.0e-5f

__device__ __forceinline__ int slow_sector(float sx, float sy) {
#pragma clang fp contract(off)
    const float RADF = (float)(180.0 / 3.14159);
    float t = atan2f(sy, sx);
    float wv = ((t * RADF) + 180.0f) / 45.0f;   // exact f32 chain as reference
    float ori = rintf(wv);                      // round-half-even == np.round
    float fr = fabsf(wv - ori);
    if (fr > 0.4995f) {
        // near a rounding tie: redo atan2 in double -> correctly-rounded f32
        double td = atan2((double)sy, (double)sx);
        float t2 = (float)td;
        wv = ((t2 * RADF) + 180.0f) / 45.0f;
        ori = rintf(wv);
    }
    return ((int)ori) & 7;
}

__global__ __launch_bounds__(256) void canny_like_kernel(const float* __restrict__ img,
                                                         float* __restrict__ out) {
#pragma clang fp contract(off)
    __shared__ float lds_g[TH + 4][TW + 4];  // gray, halo 2
    __shared__ float lds_m[TH + 2][TW + 2];  // grad magnitude, halo 1

    const int tx = threadIdx.x;              // 0..127
    const int ty = threadIdx.y;              // 0..1
    const int tid = ty * TW + tx;            // 0..255
    const int x0 = blockIdx.x * TW;
    const int y0 = blockIdx.y * TH;

    // ---- Stage 1: grayscale into LDS (tile + halo 2), zero outside image ----
    for (int i = tid; i < (TH + 4) * (TW + 4); i += 256) {
        int ry = i / (TW + 4);
        int rx = i - ry * (TW + 4);
        int gyy = y0 - 2 + ry;
        int gxx = x0 - 2 + rx;
        float v = 0.0f;
        if (gyy >= 0 && gyy < IMG_H && gxx >= 0 && gxx < IMG_W) {
            int base = gyy * IMG_W + gxx;
            float c0 = img[base];
            float c1 = img[base + IMG_H * IMG_W];
            float c2 = img[base + 2 * IMG_H * IMG_W];
            v = ((c0 + c1) + c2) / 3.0f;     // left-assoc, true division (match ref)
        }
        lds_g[ry][rx] = v;
    }
    __syncthreads();

    // ---- Stage 2: gradient magnitude into LDS (tile + halo 1) ----
    for (int i = tid; i < (TH + 2) * (TW + 2); i += 256) {
        int my = i / (TW + 2);
        int mx = i - my * (TW + 2);
        int gyy = y0 - 1 + my;
        int gxx = x0 - 1 + mx;
        float v = 0.0f;
        if (gyy >= 0 && gyy < IMG_H && gxx >= 0 && gxx < IMG_W) {
            float a00 = lds_g[my][mx],     a01 = lds_g[my][mx + 1],     a02 = lds_g[my][mx + 2];
            float a10 = lds_g[my + 1][mx],                              a12 = lds_g[my + 1][mx + 2];
            float a20 = lds_g[my + 2][mx], a21 = lds_g[my + 2][mx + 1], a22 = lds_g[my + 2][mx + 2];
            float sx = a00;
            sx = sx - a02;
            sx = sx + 2.0f * a10;
            sx = sx - 2.0f * a12;
            sx = sx + a20;
            sx = sx - a22;
            float sy = a00;
            sy = sy + 2.0f * a01;
            sy = sy + a02;
            sy = sy - a20;
            sy = sy - 2.0f * a21;
            sy = sy - a22;
            v = sqrtf(sx * sx + sy * sy);
        }
        lds_m[my][mx] = v;
    }
    __syncthreads();

    // ---- Stage 3: orientation sector + NMS + threshold ----
    for (int r = 0; r < TH / 2; ++r) {
        int oy = r * 2 + ty;                 // 0..15
        int my = oy + 1, mx = tx + 1;        // mag LDS coords of center
        int ry = oy + 2, rx = tx + 2;        // gray LDS coords of center
        float a00 = lds_g[ry - 1][rx - 1], a01 = lds_g[ry - 1][rx], a02 = lds_g[ry - 1][rx + 1];
        float a10 = lds_g[ry][rx - 1],                              a12 = lds_g[ry][rx + 1];
        float a20 = lds_g[ry + 1][rx - 1], a21 = lds_g[ry + 1][rx], a22 = lds_g[ry + 1][rx + 1];
        float sx = a00;
        sx = sx - a02;
        sx = sx + 2.0f * a10;
        sx = sx - 2.0f * a12;
        sx = sx + a20;
        sx = sx - a22;
        float sy = a00;
        sy = sy + 2.0f * a01;
        sy = sy + a02;
        sy = sy - a20;
        sy = sy - 2.0f * a21;
        sy = sy - a22;

        // Fast sector classification (no atan2): boundaries at odd multiples of
        // 22.5 scaled-degrees. Fall back to the exact atan2 path near a boundary.
        float ax = fabsf(sx), ay = fabsf(sy);
        float d1 = ay - T1_SLOPE * ax;
        float d2 = ay - T2_SLOPE * ax;
        float s = ax + ay;
        int idx;
        if (fabsf(d1) < SECT_EPS * s || fabsf(d2) < SECT_EPS * s) {
            idx = slow_sector(sx, sy);       // rare (<0.1% of pixels)
        } else if (d1 < 0.0f) {
            idx = (sx > 0.0f) ? 4 : 0;       // horizontal-ish (0 / 180 scaled-deg)
        } else if (d2 > 0.0f) {
            idx = (sy > 0.0f) ? 6 : 2;       // vertical-ish
        } else {
            idx = (sx > 0.0f) ? ((sy > 0.0f) ? 5 : 3)
                              : ((sy > 0.0f) ? 7 : 1);   // diagonals
        }
        int dxo = ((DXPACK >> (2 * idx)) & 3) - 1;
        int dyo = ((DYPACK >> (2 * idx)) & 3) - 1;

        float mc = lds_m[my][mx];
        float pos = mc - lds_m[my + dyo][mx + dxo];  // dir filter idx at p
        float neg = mc - lds_m[my - dyo][mx - dxo];  // dir filter idx+4 (opposite)
        float res = (fminf(pos, neg) > 0.0f && mc >= 0.2f) ? 1.0f : 0.0f;
        out[(y0 + oy) * IMG_W + (x0 + tx)] = res;
    }
}

extern "C" void kernel_launch(void* const* d_in, const int* in_sizes, int n_in,
                              void* d_out, int out_size, void* d_ws, size_t ws_size,
                              hipStream_t stream) {
    const float* img = (const float*)d_in[0];
    float* out = (float*)d_out;
    dim3 grid(IMG_W / TW, IMG_H / TH);   // 30 x 135, exact tiling
    dim3 block(TW, 2);
    canny_like_kernel<<<grid, block, 0, stream>>>(img, out);
}

// Round 4
// 172.636 us; speedup vs baseline: 1.0712x; 1.0340x over previous
//
#include <hip/hip_runtime.h>
#include <math.h>

#define IMG_W 3840
#define IMG_H 2160
#define TW 124          // output tile width  (31 blocks: 31*124 = 3844 >= 3840)
#define TH 16           // output tile height (135 blocks, exact)
#define LW 128          // LDS row width == blockDim.x  -> division-free mapping
#define GROWS (TH + 4)  // gray rows (halo 2)
#define MROWS (TH + 2)  // mag rows  (halo 1)

// idx -> dx [1,1,0,-1,-1,-1,0,1], dy [0,1,1,1,0,-1,-1,-1], packed as (d+1) 2-bit fields
#define DXPACK 0x901A
#define DYPACK 0x1A9

// Sector boundary slopes in the module's scaled-degree space (RAD2DEG = 180/3.14159):
// tan(22.5 * 3.14159/180), tan(67.5 * 3.14159/180)
#define T1_SLOPE 0.41421317376456f
#define T2_SLOPE 2.41420676743300f
#define SECT_EPS 3.0e-5f

__device__ __noinline__ int slow_sector(float sx, float sy) {
#pragma clang fp contract(off)
    const float RADF = (float)(180.0 / 3.14159);
    float t = atan2f(sy, sx);
    float wv = ((t * RADF) + 180.0f) / 45.0f;   // exact f32 chain as reference
    float ori = rintf(wv);                      // round-half-even == np.round
    float fr = fabsf(wv - ori);
    if (fr > 0.4995f) {
        // near a rounding tie: redo atan2 in double -> correctly-rounded f32
        double td = atan2((double)sy, (double)sx);
        float t2 = (float)td;
        wv = ((t2 * RADF) + 180.0f) / 45.0f;
        ori = rintf(wv);
    }
    return ((int)ori) & 7;
}

__global__ __launch_bounds__(256) void canny_like_kernel(const float* __restrict__ img,
                                                         float* __restrict__ out) {
#pragma clang fp contract(off)
    __shared__ float lds_g[GROWS][LW];   // gray, halo 2   (10.0 KB)
    __shared__ float lds_m[MROWS][LW];   // grad magnitude ( 9.0 KB)
    __shared__ short lds_o[MROWS][LW];   // flat NMS offset( 4.5 KB)

    const int c = threadIdx.x;                       // 0..127 == LDS column
    const int h = threadIdx.y;                       // 0..1
    const int gx = blockIdx.x * TW - 2 + c;          // image col for this thread
    const int gy0 = blockIdx.y * TH - 2;             // image row of gray LDS row 0
    const bool xok = (unsigned)gx < (unsigned)IMG_W;

    // ---- Stage 1: grayscale into LDS (tile + halo 2), zero outside image ----
    const float* p = img + gx;
    for (int i = 0; i < GROWS / 2; ++i) {
        int gy = gy0 + 2 * i + h;
        float v = 0.0f;
        if (xok && (unsigned)gy < (unsigned)IMG_H) {
            long o = (long)gy * IMG_W;
            float c0 = p[o];
            float c1 = p[o + (long)IMG_W * IMG_H];
            float c2 = p[o + 2l * IMG_W * IMG_H];
            v = ((c0 + c1) + c2) / 3.0f;             // left-assoc, true div (match ref)
        }
        lds_g[2 * i + h][c] = v;
    }
    __syncthreads();

    // ---- Stage 2: Sobel ONCE -> mag + precomputed NMS offset ----
    // grad_mag exists only on the HxW grid (dir-conv zero-pads it): mag at an
    // out-of-image center MUST be stored as 0 (this was R3's bug).
    if (c >= 1 && c <= 126) {
        for (int i = 0; i < MROWS / 2; ++i) {
            int r = 2 * i + h;                       // mag row; center image row:
            int gy = gy0 + 1 + r;
            float mag = 0.0f;
            short offp = 0;
            if (xok && (unsigned)gy < (unsigned)IMG_H) {
                float a00 = lds_g[r][c - 1],     a01 = lds_g[r][c],     a02 = lds_g[r][c + 1];
                float a10 = lds_g[r + 1][c - 1],                        a12 = lds_g[r + 1][c + 1];
                float a20 = lds_g[r + 2][c - 1], a21 = lds_g[r + 2][c], a22 = lds_g[r + 2][c + 1];
                float sx = a00;
                sx = sx - a02;
                sx = sx + 2.0f * a10;
                sx = sx - 2.0f * a12;
                sx = sx + a20;
                sx = sx - a22;
                float sy = a00;
                sy = sy + 2.0f * a01;
                sy = sy + a02;
                sy = sy - a20;
                sy = sy - 2.0f * a21;
                sy = sy - a22;
                mag = sqrtf(sx * sx + sy * sy);

                // sector -> (dx,dy) directly. Boundaries at odd multiples of 22.5
                // scaled-deg; eps band falls back to exact atan2 path. fma-vs-mul
                // skew on d1/d2 lives inside the eps band where both paths agree.
                float ax = fabsf(sx), ay = fabsf(sy);
                float d1 = fmaf(-T1_SLOPE, ax, ay);
                float d2 = fmaf(-T2_SLOPE, ax, ay);
                float s = ax + ay;
                int dxo, dyo;
                if (fabsf(d1) < SECT_EPS * s || fabsf(d2) < SECT_EPS * s) {
                    int idx = slow_sector(sx, sy);   // rare (<0.1% of pixels)
                    dxo = ((DXPACK >> (2 * idx)) & 3) - 1;
                    dyo = ((DYPACK >> (2 * idx)) & 3) - 1;
                } else {
                    dxo = (d2 > 0.0f) ? 0 : ((sx > 0.0f) ? -1 : 1);
                    dyo = (d1 < 0.0f) ? 0 : ((sy > 0.0f) ? -1 : 1);
                }
                offp = (short)(dyo * LW + dxo);      // flat float-index offset
            }
            lds_m[r][c] = mag;
            lds_o[r][c] = offp;
        }
    }
    __syncthreads();

    // ---- Stage 3: NMS + threshold (4 LDS reads, ~10 VALU) ----
    if (c >= 2 && c <= 125 && xok) {
        for (int i = 0; i < TH / 2; ++i) {
            int oy = 2 * i + h;                      // 0..15
            int mr = oy + 1;
            float mc = lds_m[mr][c];
            int off = lds_o[mr][c];
            const float* mb = &lds_m[mr][c];
            float mp = mb[off];                      // mag at (c+dx, mr+dy)
            float mn = mb[-off];                     // opposite neighbor (idx+4)
            float res = (fminf(mc - mp, mc - mn) > 0.0f && mc >= 0.2f) ? 1.0f : 0.0f;
            out[(long)(gy0 + 2 + oy) * IMG_W + gx] = res;
        }
    }
}

extern "C" void kernel_launch(void* const* d_in, const int* in_sizes, int n_in,
                              void* d_out, int out_size, void* d_ws, size_t ws_size,
                              hipStream_t stream) {
    const float* img = (const float*)d_in[0];
    float* out = (float*)d_out;
    dim3 grid((IMG_W + TW - 1) / TW, IMG_H / TH);    // 31 x 135
    dim3 block(LW, 2);
    canny_like_kernel<<<grid, block, 0, stream>>>(img, out);
}

// Round 6
// 166.294 us; speedup vs baseline: 1.1121x; 1.0381x over previous
//
#include <hip/hip_runtime.h>
#include <math.h>

#define IMG_W 3840
#define IMG_H 2160
#define OUTW  60        // output columns per wave strip (64 lanes - 4 halo)
#define R     20        // output rows per strip (2160 = 108 * 20, exact)
#define ITERS (R + 4)   // 24 gray rows loaded per strip
#define MROWS (R + 2)   // 22 mag rows in wave-private LDS

// idx -> dx [1,1,0,-1,-1,-1,0,1], dy [0,1,1,1,0,-1,-1,-1], packed as (d+1) 2-bit fields
#define DXPACK 0x901A
#define DYPACK 0x1A9

// Sector boundary slopes in the module's scaled-degree space (RAD2DEG = 180/3.14159):
// tan(22.5 * 3.14159/180), tan(67.5 * 3.14159/180)
#define T1_SLOPE 0.41421317376456f
#define T2_SLOPE 2.41420676743300f
#define SECT_EPS 3.0e-5f

__device__ __noinline__ int slow_sector(float sx, float sy) {
#pragma clang fp contract(off)
    const float RADF = (float)(180.0 / 3.14159);
    float t = atan2f(sy, sx);
    float wv = ((t * RADF) + 180.0f) / 45.0f;   // exact f32 chain as reference
    float ori = rintf(wv);                      // round-half-even == np.round
    float fr = fabsf(wv - ori);
    if (fr > 0.4995f) {
        // near a rounding tie: redo atan2 in double -> correctly-rounded f32
        double td = atan2((double)sy, (double)sx);
        float t2 = (float)td;
        wv = ((t2 * RADF) + 180.0f) / 45.0f;
        ori = rintf(wv);
    }
    return ((int)ori) & 7;
}

__global__ __launch_bounds__(256, 4) void canny_like_kernel(const float* __restrict__ img,
                                                            float* __restrict__ out) {
#pragma clang fp contract(off)
    // wave-private mag strips: no cross-wave sharing -> NO barriers anywhere
    __shared__ float lds_m[4][MROWS][64];        // 22.0 KB/block

    const int lane = threadIdx.x;                // 0..63
    const int w    = threadIdx.y;                // wave id in block, 0..3
    const int X0   = (blockIdx.x * 4 + w) * OUTW;
    const int Y0   = blockIdx.y * R;
    const int x    = X0 - 2 + lane;              // gray column owned by this lane
    const bool xok    = (unsigned)x < (unsigned)IMG_W;
    const int  xc     = min(max(x, 0), IMG_W - 1);       // clamped (safe addr, value masked)
    const bool xmok   = (lane >= 1) && (lane <= 62) && xok;   // mag-valid lanes
    const bool xoutok = (lane >= 2) && (lane <= 61);          // output lanes

    const float* im1 = img + (size_t)IMG_W * IMG_H;
    const float* im2 = img + 2 * (size_t)IMG_W * IMG_H;

    float gl[3], gc[3], gr[3];                   // rolling gray rows (left/center/right)
    float mc_p = 0.0f;                           // mag of pending NMS row (lag 1)
    int   off_p = 0;                             // its flat NMS offset (lag 1)

#pragma unroll
    for (int k = 0; k < ITERS; ++k) {
        // ---- load gray row y = Y0-2+k (uniform y-guard, per-lane x-guard) ----
        const int y = Y0 - 2 + k;
        float g = 0.0f;
        if ((unsigned)y < (unsigned)IMG_H) {     // wave-uniform branch
            int o = y * IMG_W + xc;
            float c0 = img[o], c1 = im1[o], c2 = im2[o];
            float t = ((c0 + c1) + c2) / 3.0f;   // left-assoc, true div (match ref)
            g = xok ? t : 0.0f;
        }
        const int s = k % 3;                     // compile-time after full unroll
        gc[s] = g;
        gl[s] = __shfl_up(g, 1);                 // lane i <- gray(x-1)
        gr[s] = __shfl_down(g, 1);               // lane i <- gray(x+1)

        if (k >= 2) {
            // ---- mag row m = y-1 from gray rows y-2,y-1,y ----
            const int i0 = (k - 2) % 3, i1 = (k - 1) % 3, i2 = k % 3;
            float a00 = gl[i0], a01 = gc[i0], a02 = gr[i0];
            float a10 = gl[i1],               a12 = gr[i1];
            float a20 = gl[i2], a21 = gc[i2], a22 = gr[i2];
            float sx = a00;                      // exact R4 tap order
            sx = sx - a02;
            sx = sx + 2.0f * a10;
            sx = sx - 2.0f * a12;
            sx = sx + a20;
            sx = sx - a22;
            float sy = a00;
            sy = sy + 2.0f * a01;
            sy = sy + a02;
            sy = sy - a20;
            sy = sy - 2.0f * a21;
            sy = sy - a22;
            float magv = sqrtf(sx * sx + sy * sy);

            // sector -> (dx,dy); eps band falls back to exact atan2 path (rare)
            float ax = fabsf(sx), ay = fabsf(sy);
            float d1 = fmaf(-T1_SLOPE, ax, ay);
            float d2 = fmaf(-T2_SLOPE, ax, ay);
            float sA = ax + ay;
            int dxo, dyo;
            if (__builtin_expect(fabsf(d1) < SECT_EPS * sA || fabsf(d2) < SECT_EPS * sA, 0)) {
                int idx = slow_sector(sx, sy);
                dxo = ((DXPACK >> (2 * idx)) & 3) - 1;
                dyo = ((DYPACK >> (2 * idx)) & 3) - 1;
            } else {
                dxo = (d2 > 0.0f) ? 0 : ((sx > 0.0f) ? -1 : 1);
                dyo = (d1 < 0.0f) ? 0 : ((sy > 0.0f) ? -1 : 1);
            }
            // grad_mag exists only on the HxW grid (dir-conv zero-pads it)
            const bool vok = xmok && ((unsigned)(y - 1) < (unsigned)IMG_H);
            float mag = vok ? magv : 0.0f;
            int  offv = vok ? (dyo * 64 + dxo) : 0;

            lds_m[w][k - 2][lane] = mag;         // ds_write, immediate offset

            // ---- NMS for row n = y-2 (mag rows n-1,n,n+1 all written; same-wave
            //      DS ops are in-order on CDNA -> no barrier needed) ----
            if (k >= 4) {
                const float* cb = &lds_m[w][k - 3][lane];
                float mp = cb[off_p];            // mag at (x+dx, n+dy)
                float mn = cb[-off_p];           // opposite neighbor (idx+4)
                float res = (fminf(mc_p - mp, mc_p - mn) > 0.0f && mc_p >= 0.2f) ? 1.0f : 0.0f;
                if (xoutok)
                    out[(size_t)(Y0 + k - 4) * IMG_W + x] = res;
            }
            mc_p = mag;
            off_p = offv;
        }
    }
}

extern "C" void kernel_launch(void* const* d_in, const int* in_sizes, int n_in,
                              void* d_out, int out_size, void* d_ws, size_t ws_size,
                              hipStream_t stream) {
    const float* img = (const float*)d_in[0];
    float* out = (float*)d_out;
    // 64 x-strips (60 cols each, 64*60 = 3840 exact) x 108 y-strips (20 rows, exact)
    dim3 grid(64 / 4, IMG_H / R);                // (16, 108) = 1728 blocks, 4 waves each
    dim3 block(64, 4);
    canny_like_kernel<<<grid, block, 0, stream>>>(img, out);
}